// Round 5
// baseline (176.306 us; speedup 1.0000x reference)
//
#include <hip/hip_runtime.h>

// NCE loss: out0 = align + w*uniform, out1 = align, out2 = uniform
// align[n]   = logsig(ref[n]·pos[n]/T)
// uniform[n] = mean_m logsig(-ref[n]·neg[m]/T)
// N=M=8192, D=512, T=0.5, w=1.0
//
// nce_gemm: persistent 256-block kernel; per block 4 output tiles of
// 256x256 (same A rows), BK=64, 8 waves (2x4), 32x32x16 MFMA,
// m201-faithful phases: {reads; stage; [vmcnt]; bar; setprio MFMA; bar}.

typedef __attribute__((ext_vector_type(8))) short short8;
typedef __attribute__((ext_vector_type(8))) unsigned short ushort8;
typedef __attribute__((ext_vector_type(4))) float f32x4;
typedef __attribute__((ext_vector_type(16))) float f32x16;

constexpr int N_ = 8192;
constexpr int M_ = 8192;
constexpr int D_ = 512;
constexpr float INV_T = 2.0f;
constexpr float NEG_W = 1.0f;
constexpr float LOG2E = 1.4426950408889634f;
constexpr float LN2   = 0.6931471805599453f;

__device__ __forceinline__ unsigned short f2bf(float f) {
  unsigned int u = __builtin_bit_cast(unsigned int, f);
  u += 0x7FFFu + ((u >> 16) & 1u);  // RNE
  return (unsigned short)(u >> 16);
}

__device__ __forceinline__ float logsig_neg(float s) {
  // log sigmoid(-s) = min(-s,0) - log1p(exp(-|s|))
  float t = __builtin_fabsf(s);
  float e = __builtin_amdgcn_exp2f(-t * LOG2E);
  float l = __builtin_amdgcn_logf(1.0f + e) * LN2;
  return fminf(-s, 0.0f) - l;
}

// fp32 -> bf16 with intra-row 16B-chunk XOR involution pre-applied
// (chunk c stored at c ^ (row&7) within each 128B K-segment) so linear
// global_load_lds staging yields the swizzled LDS layout (rule #21).
__global__ __launch_bounds__(256) void cvt_pack(
    const float* __restrict__ refp, const float* __restrict__ negp,
    unsigned short* __restrict__ abf, unsigned short* __restrict__ bbf) {
  const int b = blockIdx.x;
  const float* src = (b < 2048) ? refp : negp;
  unsigned short* dst = (b < 2048) ? abf : bbf;
  const int i = (b & 2047) * 256 + threadIdx.x;  // 16B-chunk index
  const f32x4* s = reinterpret_cast<const f32x4*>(src) + (size_t)i * 2;
  f32x4 v0 = s[0], v1 = s[1];
  ushort8 o;
#pragma unroll
  for (int j = 0; j < 4; ++j) {
    o[j]     = f2bf(v0[j]);
    o[4 + j] = f2bf(v1[j]);
  }
  const unsigned int row = (unsigned int)i >> 6;
  const unsigned int seg = ((unsigned int)i >> 3) & 7;
  const unsigned int c   = (unsigned int)i & 7;
  const size_t byte =
      (size_t)row * 1024 + seg * 128 + (size_t)((c ^ (row & 7u)) << 4);
  *reinterpret_cast<ushort8*>(reinterpret_cast<char*>(dst) + byte) = o;
}

#define VMCNT(n) asm volatile("s_waitcnt vmcnt(" #n ")" ::: "memory")
#define BAR()                              \
  {                                        \
    asm volatile("" ::: "memory");         \
    __builtin_amdgcn_s_barrier();          \
    asm volatile("" ::: "memory");         \
  }

__global__ __launch_bounds__(512, 2) void nce_gemm(
    const unsigned short* __restrict__ A,  // ref bf16, pre-swizzled rows
    const unsigned short* __restrict__ B,  // neg bf16, pre-swizzled rows
    float* __restrict__ rowsum) {          // (N,) fp32, pre-zeroed
  extern __shared__ char lds[];
  char* As = lds;           // 2 bufs x 256 rows x 128 B
  char* Bs = lds + 65536;   // 2 bufs x 256 rows x 128 B

  const int tid  = threadIdx.x;
  const int lane = tid & 63;
  const int wid  = tid >> 6;   // 0..7
  const int wr   = wid >> 2;   // 0..1 (A half: 128 rows)
  const int wc   = wid & 3;    // 0..3 (B quarter: 64 cols)
  const int l31  = lane & 31;
  const int l5   = lane >> 5;

  // persistent: 256 blocks, 4 tiles each. XCD x keeps A rows x*1024..+1024
  // (1 MB, L2-resident); block keeps ONE 256-row A band for all 4 tiles.
  const int cu   = blockIdx.x;   // 0..255
  const int x    = cu & 7;       // XCD
  const int q    = cu >> 3;      // 0..31
  const int band = q & 3;
  const int col0 = q >> 3;       // 0..7; tile tau -> bcol (col0 + 8*tau)*256
  const int brow = (x * 4 + band) * 256;

  // staging lane address (global stored layout == desired LDS layout)
  const size_t laneoff = (size_t)(lane >> 3) * 1024 + (size_t)(lane & 7) * 16;
  const char* gAl = reinterpret_cast<const char*>(A) + (size_t)brow * 1024 + laneoff;
  const char* gB0 = reinterpret_cast<const char*>(B) + (size_t)col0 * 262144 + laneoff;

  f32x16 acc[4][2];
#pragma unroll
  for (int i = 0; i < 4; ++i)
#pragma unroll
    for (int j = 0; j < 2; ++j) acc[i][j] = (f32x16)0.0f;

  short8 a[2][4], b0v[4], b1v[4];

  // stage one half-tile (16 KiB = 128 rows x 128 B), 2 glds per thread
#define STAGE_A(g, h)                                                         \
  {                                                                           \
    _Pragma("unroll") for (int j = 0; j < 2; ++j) {                           \
      const int rb = (h) * 128 + (wid * 2 + j) * 8;                           \
      __builtin_amdgcn_global_load_lds(                                       \
          (const __attribute__((address_space(1))) unsigned int*)(            \
              gAl + (size_t)rb * 1024 + ((g) & 7) * 128),                     \
          (__attribute__((address_space(3))) unsigned int*)(                  \
              As + ((g) & 1) * 32768 + rb * 128),                             \
          16, 0, 0);                                                          \
    }                                                                         \
  }
#define STAGE_B(g, h, BB)                                                     \
  {                                                                           \
    _Pragma("unroll") for (int j = 0; j < 2; ++j) {                           \
      const int rb = (h) * 128 + (wid * 2 + j) * 8;                           \
      __builtin_amdgcn_global_load_lds(                                       \
          (const __attribute__((address_space(1))) unsigned int*)(            \
              (BB) + (size_t)rb * 1024 + ((g) & 7) * 128),                    \
          (__attribute__((address_space(3))) unsigned int*)(                  \
              Bs + ((g) & 1) * 32768 + rb * 128),                             \
          16, 0, 0);                                                          \
    }                                                                         \
  }

  // fragment reads (32x32x16: lane holds row l31, k = l5*8 + j within kstep)
#define READ_A(buf, mp)                                                       \
  {                                                                           \
    _Pragma("unroll") for (int mf = 0; mf < 2; ++mf) {                        \
      const int row = wr * 128 + (mp)*64 + mf * 32 + l31;                     \
      const char* base = As + (buf)*32768 + row * 128;                        \
      _Pragma("unroll") for (int ks = 0; ks < 4; ++ks) {                      \
        const int c = ks * 2 + l5;                                            \
        a[mf][ks] =                                                           \
            *reinterpret_cast<const short8*>(base + ((c ^ (row & 7)) << 4));  \
      }                                                                       \
    }                                                                         \
  }
#define READ_B(buf, nf, DST)                                                  \
  {                                                                           \
    const int row = wc * 64 + (nf)*32 + l31;                                  \
    const char* base = Bs + (buf)*32768 + row * 128;                          \
    _Pragma("unroll") for (int ks = 0; ks < 4; ++ks) {                        \
      const int c = ks * 2 + l5;                                              \
      DST[ks] =                                                               \
          *reinterpret_cast<const short8*>(base + ((c ^ (row & 7)) << 4));    \
    }                                                                         \
  }

  // 8 MFMA (2 m-frags x 1 n-frag x 4 ksteps)
#define MFMA8(mp, nf, BV)                                                     \
  {                                                                           \
    __builtin_amdgcn_s_setprio(1);                                            \
    _Pragma("unroll") for (int ks = 0; ks < 4; ++ks)                          \
    _Pragma("unroll") for (int mf = 0; mf < 2; ++mf)                          \
      acc[(mp)*2 + mf][nf] = __builtin_amdgcn_mfma_f32_32x32x16_bf16(         \
          a[mf][ks], BV[ks], acc[(mp)*2 + mf][nf], 0, 0, 0);                  \
    __builtin_amdgcn_s_setprio(0);                                            \
  }

  // prologue: tile0 full + tile1 B-h0 (10 loads); leave newest 2 in flight
  STAGE_B(0, 0, gB0);
  STAGE_B(0, 1, gB0);
  STAGE_A(0, 0);
  STAGE_A(0, 1);
  STAGE_B(1, 0, gB0);
  VMCNT(2);
  BAR();

#pragma unroll 1
  for (int tau = 0; tau < 4; ++tau) {
    const char* Bc = gB0 + (size_t)tau * 2097152;            // this tile's B
    const char* Bn = (tau < 3) ? (Bc + 2097152) : Bc;        // next (clamped)

#pragma unroll
    for (int it = 0; it < 4; ++it) {
      const int e  = 2 * it;          // even K-tile (buf0)
      const int g1 = e + 1;           // staged ph1-3 (B h1, A h0, A h1)
      const int g2 = e + 2;           // staged ph4-7; rolls to next tile at it=3
      const int g3 = e + 3;           // B h0 staged ph8
      const char* B2 = (it == 3) ? Bn : Bc;

      // ph1: quadrant (mp0, n0) of tile e
      READ_A(0, 0);
      READ_B(0, 0, b0v);
      STAGE_B(g1, 1, Bc);
      BAR();
      MFMA8(0, 0, b0v);
      BAR();
      // ph2: (mp0, n1)
      READ_B(0, 1, b1v);
      STAGE_A(g1, 0);
      BAR();
      MFMA8(0, 1, b1v);
      BAR();
      // ph3: (mp1, n0)
      READ_A(0, 1);
      STAGE_A(g1, 1);
      BAR();
      MFMA8(1, 0, b0v);
      BAR();
      // ph4: (mp1, n1); guarantee tile g1 (buf1) before ph5 reads
      STAGE_B(g2, 0, B2);
      VMCNT(2);
      BAR();
      MFMA8(1, 1, b1v);
      BAR();
      // ph5: tile e+1 (buf1), (mp0, n0)
      READ_A(1, 0);
      READ_B(1, 0, b0v);
      STAGE_B(g2, 1, B2);
      BAR();
      MFMA8(0, 0, b0v);
      BAR();
      // ph6: (mp0, n1)
      READ_B(1, 1, b1v);
      STAGE_A(g2, 0);
      BAR();
      MFMA8(0, 1, b1v);
      BAR();
      // ph7: (mp1, n0)
      READ_A(1, 1);
      STAGE_A(g2, 1);
      BAR();
      MFMA8(1, 0, b0v);
      BAR();
      // ph8: (mp1, n1); guarantee tile g2 (buf0) before next ph1 reads
      STAGE_B(g3, 0, B2);
      VMCNT(2);
      BAR();
      MFMA8(1, 1, b1v);
      BAR();
    }

    // epilogue for tile tau: uni = logsig(-s*INV_T); reduce 64 cols/wave;
    // overlaps the already-issued next-tile staging.
#pragma unroll
    for (int mf2 = 0; mf2 < 4; ++mf2) {
      float v[16];
#pragma unroll
      for (int rg = 0; rg < 16; ++rg)
        v[rg] = logsig_neg(acc[mf2][0][rg] * INV_T) +
                logsig_neg(acc[mf2][1][rg] * INV_T);
#pragma unroll
      for (int rg = 0; rg < 16; ++rg) {
        float t = v[rg];
        t += __shfl_xor(t, 1);
        t += __shfl_xor(t, 2);
        t += __shfl_xor(t, 4);
        t += __shfl_xor(t, 8);
        t += __shfl_xor(t, 16);
        v[rg] = t;
      }
      if (l31 == 0) {
#pragma unroll
        for (int rg = 0; rg < 16; ++rg) {
          const int row =
              brow + wr * 128 + mf2 * 32 + (rg & 3) + 8 * (rg >> 2) + 4 * l5;
          atomicAdd(&rowsum[row], v[rg]);
        }
      }
      acc[mf2][0] = (f32x16)0.0f;
      acc[mf2][1] = (f32x16)0.0f;
    }
  }
#undef STAGE_A
#undef STAGE_B
#undef READ_A
#undef READ_B
#undef MFMA8
}

__global__ __launch_bounds__(256) void nce_combine(
    const float* __restrict__ ref, const float* __restrict__ pos,
    const float* __restrict__ rowsum, float* __restrict__ out) {
  const int wid  = threadIdx.x >> 6;
  const int lane = threadIdx.x & 63;
  const int n    = blockIdx.x * 4 + wid;

  const f32x4* pr =
      reinterpret_cast<const f32x4*>(ref + (size_t)n * D_ + lane * 8);
  const f32x4* pp =
      reinterpret_cast<const f32x4*>(pos + (size_t)n * D_ + lane * 8);
  f32x4 a0 = pr[0], a1 = pr[1], b0 = pp[0], b1 = pp[1];
  float d = 0.0f;
#pragma unroll
  for (int i = 0; i < 4; ++i) d = __builtin_fmaf(a0[i], b0[i], d);
#pragma unroll
  for (int i = 0; i < 4; ++i) d = __builtin_fmaf(a1[i], b1[i], d);
#pragma unroll
  for (int s = 1; s < 64; s <<= 1) d += __shfl_xor(d, s);

  if (lane == 0) {
    float z = d * INV_T;
    float align   = logsig_neg(-z);
    float uniform = rowsum[n] * (1.0f / (float)M_);
    out[n]          = align + NEG_W * uniform;
    out[N_ + n]     = align;
    out[2 * N_ + n] = uniform;
  }
}

extern "C" void kernel_launch(void* const* d_in, const int* in_sizes, int n_in,
                              void* d_out, int out_size, void* d_ws,
                              size_t ws_size, hipStream_t stream) {
  const float* ref = (const float*)d_in[0];
  const float* pos = (const float*)d_in[1];
  const float* neg = (const float*)d_in[2];
  float* out = (float*)d_out;

  float* rowsum = (float*)d_ws;                                  // 32 KB
  unsigned short* abf = (unsigned short*)((char*)d_ws + 32768);  // 8 MB
  unsigned short* bbf = abf + (size_t)N_ * D_;                   // 8 MB

  (void)hipFuncSetAttribute((const void*)nce_gemm,
                            hipFuncAttributeMaxDynamicSharedMemorySize,
                            131072);

  hipMemsetAsync(rowsum, 0, N_ * sizeof(float), stream);
  cvt_pack<<<4096, 256, 0, stream>>>(ref, neg, abf, bbf);
  nce_gemm<<<256, 512, 131072, stream>>>(abf, bbf, rowsum);
  nce_combine<<<N_ / 4, 256, 0, stream>>>(ref, pos, rowsum, out);
}

// Round 6
// 118.010 us; speedup vs baseline: 1.4940x; 1.4940x over previous
//
#include <hip/hip_runtime.h>

// NCE loss: out0 = align + w*uniform, out1 = align, out2 = uniform
// align[n]   = logsig(ref[n]·pos[n]/T)
// uniform[n] = mean_m logsig(-ref[n]·neg[m]/T)
// N=M=8192, D=512, T=0.5, w=1.0
//
// nce_gemm: 256x256 tile, BK=64, 8 waves (2x4), 16x16x32 MFMA, m201-style
// 8-phase schedule: {reads; stage; [vmcnt(4)]; bar; lgkm0; setprio MFMA; bar}.
// Stage-half split matches consumption order; every half-tile's vmcnt lands
// one phase before its first read.

typedef __attribute__((ext_vector_type(8))) short short8;
typedef __attribute__((ext_vector_type(8))) unsigned short ushort8;
typedef __attribute__((ext_vector_type(4))) float f32x4;

constexpr int N_ = 8192;
constexpr int M_ = 8192;
constexpr int D_ = 512;
constexpr float INV_T = 2.0f;
constexpr float NEG_W = 1.0f;
constexpr float LOG2E = 1.4426950408889634f;
constexpr float LN2   = 0.6931471805599453f;

__device__ __forceinline__ unsigned short f2bf(float f) {
  unsigned int u = __builtin_bit_cast(unsigned int, f);
  u += 0x7FFFu + ((u >> 16) & 1u);  // RNE
  return (unsigned short)(u >> 16);
}

__device__ __forceinline__ float logsig_neg(float s) {
  // log sigmoid(-s) = min(-s,0) - log1p(exp(-|s|))
  float t = __builtin_fabsf(s);
  float e = __builtin_amdgcn_exp2f(-t * LOG2E);
  float l = __builtin_amdgcn_logf(1.0f + e) * LN2;
  return fminf(-s, 0.0f) - l;
}

// fp32 -> bf16 with intra-row 16B-chunk XOR involution pre-applied
// (chunk c stored at c ^ (row&7) within each 128B K-segment) so linear
// global_load_lds staging yields the swizzled LDS layout (rule #21).
__global__ __launch_bounds__(256) void cvt_pack(
    const float* __restrict__ refp, const float* __restrict__ negp,
    unsigned short* __restrict__ abf, unsigned short* __restrict__ bbf) {
  const int b = blockIdx.x;
  const float* src = (b < 2048) ? refp : negp;
  unsigned short* dst = (b < 2048) ? abf : bbf;
  const int i = (b & 2047) * 256 + threadIdx.x;  // 16B-chunk index
  const f32x4* s = reinterpret_cast<const f32x4*>(src) + (size_t)i * 2;
  f32x4 v0 = s[0], v1 = s[1];
  ushort8 o;
#pragma unroll
  for (int j = 0; j < 4; ++j) {
    o[j]     = f2bf(v0[j]);
    o[4 + j] = f2bf(v1[j]);
  }
  const unsigned int row = (unsigned int)i >> 6;
  const unsigned int seg = ((unsigned int)i >> 3) & 7;
  const unsigned int c   = (unsigned int)i & 7;
  const size_t byte =
      (size_t)row * 1024 + seg * 128 + (size_t)((c ^ (row & 7u)) << 4);
  *reinterpret_cast<ushort8*>(reinterpret_cast<char*>(dst) + byte) = o;
}

__global__ __launch_bounds__(512, 2) void nce_gemm(
    const unsigned short* __restrict__ A,  // ref bf16, pre-swizzled rows
    const unsigned short* __restrict__ B,  // neg bf16, pre-swizzled rows
    float* __restrict__ rowsum) {          // (N,) fp32, pre-zeroed
  extern __shared__ char lds[];
  char* As = lds;           // 2 bufs x 256 rows x 128 B
  char* Bs = lds + 65536;   // 2 bufs x 256 rows x 128 B

  const int tid  = threadIdx.x;
  const int lane = tid & 63;
  const int wid  = tid >> 6;   // 0..7
  const int wr   = wid >> 2;   // 0..1 (A half: 128 rows)
  const int wc   = wid & 3;    // 0..3 (B quarter: 64 cols)

  // XCD band swizzle: 1024 blocks, 8 XCDs, 4 row-bands/XCD, col-major in band
  const int bid  = blockIdx.x;
  const int x    = bid & 7;
  const int t    = bid >> 3;  // 0..127
  const int brow = (x * 4 + (t & 3)) * 256;
  const int bcol = (t >> 2) * 256;

  // staging lane address (global stored layout == desired LDS layout)
  const size_t laneoff = (size_t)(lane >> 3) * 1024 + (size_t)(lane & 7) * 16;
  const char* gA = reinterpret_cast<const char*>(A) + (size_t)brow * 1024 + laneoff;
  const char* gB = reinterpret_cast<const char*>(B) + (size_t)bcol * 1024 + laneoff;

  // fragment-read constants (proven conflict-free 16-lane pattern)
  const int r  = lane & 15;
  const int g4 = lane >> 4;
  const int c0 = ((g4 ^ (r & 7)) << 4);
  const int c1 = (((4 + g4) ^ (r & 7)) << 4);

  f32x4 acc[8][4] = {};
  short8 aLo[4][2], aHi[4][2], bv0[2][2], bv1[2][2];

  // ---- stage one half-tile (16 KiB), 2 glds per thread ----
  // A-sh h: rows [64h,64h+64) U [128+64h,192+64h)  (mp=h read rows)
#define STAGE_A(g, h)                                                         \
  {                                                                           \
    _Pragma("unroll") for (int j = 0; j < 2; ++j) {                           \
      const int u  = wid * 2 + j;                                             \
      const int rb = (u >> 3) * 128 + (u & 7) * 8 + (h) * 64;                 \
      __builtin_amdgcn_global_load_lds(                                       \
          (const __attribute__((address_space(1))) unsigned int*)(            \
              gA + (size_t)rb * 1024 + (size_t)((g) & 7) * 128),              \
          (__attribute__((address_space(3))) unsigned int*)(                  \
              As + ((g) & 1) * 32768 + rb * 128),                             \
          16, 0, 0);                                                          \
    }                                                                         \
  }
  // B-sh h: rows == [32h, 32h+32) mod 64  (nh=h read rows)
#define STAGE_B(g, h)                                                         \
  {                                                                           \
    _Pragma("unroll") for (int j = 0; j < 2; ++j) {                           \
      const int u  = wid * 2 + j;                                             \
      const int rb = (u >> 2) * 64 + (u & 3) * 8 + (h) * 32;                  \
      __builtin_amdgcn_global_load_lds(                                       \
          (const __attribute__((address_space(1))) unsigned int*)(            \
              gB + (size_t)rb * 1024 + (size_t)((g) & 7) * 128),              \
          (__attribute__((address_space(3))) unsigned int*)(                  \
              Bs + ((g) & 1) * 32768 + rb * 128),                             \
          16, 0, 0);                                                          \
    }                                                                         \
  }

#define READ_A(buf, mp, DST)                                                  \
  {                                                                           \
    _Pragma("unroll") for (int mf = 0; mf < 4; ++mf) {                        \
      const int ro = (wr * 128 + (mp)*64 + mf * 16 + r) * 128;                \
      DST[mf][0] =                                                            \
          *reinterpret_cast<const short8*>(As + (buf)*32768 + ro + c0);       \
      DST[mf][1] =                                                            \
          *reinterpret_cast<const short8*>(As + (buf)*32768 + ro + c1);       \
    }                                                                         \
  }
#define READ_B(buf, nh, DST)                                                  \
  {                                                                           \
    _Pragma("unroll") for (int nf = 0; nf < 2; ++nf) {                        \
      const int ro = (wc * 64 + (nh)*32 + nf * 16 + r) * 128;                 \
      DST[nf][0] =                                                            \
          *reinterpret_cast<const short8*>(Bs + (buf)*32768 + ro + c0);       \
      DST[nf][1] =                                                            \
          *reinterpret_cast<const short8*>(Bs + (buf)*32768 + ro + c1);       \
    }                                                                         \
  }

#define WAITBAR()                                                             \
  {                                                                           \
    asm volatile("s_waitcnt vmcnt(4)" ::: "memory");                          \
    __builtin_amdgcn_s_barrier();                                             \
    asm volatile("s_waitcnt lgkmcnt(0)" ::: "memory");                        \
    __builtin_amdgcn_sched_barrier(0);                                        \
  }
#define NOWAITBAR()                                                           \
  {                                                                           \
    asm volatile("" ::: "memory");                                            \
    __builtin_amdgcn_s_barrier();                                             \
    asm volatile("s_waitcnt lgkmcnt(0)" ::: "memory");                        \
    __builtin_amdgcn_sched_barrier(0);                                        \
  }
#define ENDBAR()                                                              \
  {                                                                           \
    asm volatile("" ::: "memory");                                            \
    __builtin_amdgcn_s_barrier();                                             \
    asm volatile("" ::: "memory");                                            \
  }

#define CLUSTER(mp, nh, AV, BV)                                               \
  {                                                                           \
    __builtin_amdgcn_s_setprio(1);                                            \
    _Pragma("unroll") for (int k = 0; k < 2; ++k)                             \
    _Pragma("unroll") for (int mf = 0; mf < 4; ++mf)                          \
    _Pragma("unroll") for (int nf = 0; nf < 2; ++nf)                          \
      acc[(mp)*4 + mf][(nh)*2 + nf] = __builtin_amdgcn_mfma_f32_16x16x32_bf16(\
          AV[mf][k], BV[nf][k], acc[(mp)*4 + mf][(nh)*2 + nf], 0, 0, 0);      \
    __builtin_amdgcn_s_setprio(0);                                            \
    __builtin_amdgcn_sched_barrier(0);                                        \
  }

  // ---- prologue: tile 0 into buf0 (8 loads), mimic steady-state ph8 tail
  STAGE_A(0, 0);
  STAGE_B(0, 0);
  STAGE_A(0, 1);
  STAGE_B(0, 1);
  asm volatile("s_waitcnt vmcnt(4)" ::: "memory");  // A-sh0,B-sh0 landed
  ENDBAR();

  // ---- main loop: 4 iters x {tile e in buf0, tile e+1 in buf1} ----
#pragma unroll
  for (int it = 0; it < 4; ++it) {
    const int e = 2 * it;
    // ph1: (m0,n0) of tile e
    READ_A(0, 0, aLo);
    READ_B(0, 0, bv0);
    STAGE_A(e + 1, 0);
    WAITBAR();          // retires A-sh1(buf0)  -> read ph2
    CLUSTER(0, 0, aLo, bv0);
    ENDBAR();
    // ph2: (m1,n0)
    READ_A(0, 1, aHi);
    STAGE_B(e + 1, 0);
    WAITBAR();          // retires B-sh1(buf0)  -> read ph3
    CLUSTER(1, 0, aHi, bv0);
    ENDBAR();
    // ph3: (m0,n1)
    READ_B(0, 1, bv1);
    STAGE_A(e + 1, 1);
    NOWAITBAR();
    CLUSTER(0, 1, aLo, bv1);
    ENDBAR();
    // ph4: (m1,n1)
    STAGE_B(e + 1, 1);
    WAITBAR();          // retires A-sh0,B-sh0(buf1) -> read ph5
    CLUSTER(1, 1, aHi, bv1);
    ENDBAR();
    // ph5: (m0,n0) of tile e+1
    READ_A(1, 0, aLo);
    READ_B(1, 0, bv0);
    STAGE_A(e + 2, 0);
    WAITBAR();          // retires A-sh1(buf1)  -> read ph6
    CLUSTER(0, 0, aLo, bv0);
    ENDBAR();
    // ph6: (m1,n0)
    READ_A(1, 1, aHi);
    STAGE_B(e + 2, 0);
    WAITBAR();          // retires B-sh1(buf1)  -> read ph7
    CLUSTER(1, 0, aHi, bv0);
    ENDBAR();
    // ph7: (m0,n1)
    READ_B(1, 1, bv1);
    STAGE_A(e + 2, 1);
    NOWAITBAR();
    CLUSTER(0, 1, aLo, bv1);
    ENDBAR();
    // ph8: (m1,n1)
    STAGE_B(e + 2, 1);
    WAITBAR();          // retires A-sh0,B-sh0(buf0 next) -> read next ph1
    CLUSTER(1, 1, aHi, bv1);
    ENDBAR();
  }
  asm volatile("s_waitcnt vmcnt(0)" ::: "memory");  // retire tail stages
#undef STAGE_A
#undef STAGE_B
#undef READ_A
#undef READ_B
#undef CLUSTER

  // ---- epilogue: uni = logsig(-s*INV_T); reduce this wave's 64 cols ----
  float part[32];
#pragma unroll
  for (int am = 0; am < 8; ++am)
#pragma unroll
    for (int rr = 0; rr < 4; ++rr) {
      float ssum = 0.0f;
#pragma unroll
      for (int an = 0; an < 4; ++an) {
        float s = acc[am][an][rr] * INV_T;
        ssum += logsig_neg(s);
      }
      part[am * 4 + rr] = ssum;
    }
#pragma unroll
  for (int i = 0; i < 32; ++i) {
    float v = part[i];
    v += __shfl_xor(v, 1);
    v += __shfl_xor(v, 2);
    v += __shfl_xor(v, 4);
    v += __shfl_xor(v, 8);
    part[i] = v;
  }
  if ((lane & 15) == 0) {
    const int gq = lane >> 4;  // row quad within fragment
#pragma unroll
    for (int am = 0; am < 8; ++am)
#pragma unroll
      for (int rr = 0; rr < 4; ++rr)
        atomicAdd(&rowsum[brow + wr * 128 + am * 16 + gq * 4 + rr],
                  part[am * 4 + rr]);
  }
}

__global__ __launch_bounds__(256) void nce_combine(
    const float* __restrict__ ref, const float* __restrict__ pos,
    const float* __restrict__ rowsum, float* __restrict__ out) {
  const int wid  = threadIdx.x >> 6;
  const int lane = threadIdx.x & 63;
  const int n    = blockIdx.x * 4 + wid;

  const f32x4* pr =
      reinterpret_cast<const f32x4*>(ref + (size_t)n * D_ + lane * 8);
  const f32x4* pp =
      reinterpret_cast<const f32x4*>(pos + (size_t)n * D_ + lane * 8);
  f32x4 a0 = pr[0], a1 = pr[1], b0 = pp[0], b1 = pp[1];
  float d = 0.0f;
#pragma unroll
  for (int i = 0; i < 4; ++i) d = __builtin_fmaf(a0[i], b0[i], d);
#pragma unroll
  for (int i = 0; i < 4; ++i) d = __builtin_fmaf(a1[i], b1[i], d);
#pragma unroll
  for (int s = 1; s < 64; s <<= 1) d += __shfl_xor(d, s);

  if (lane == 0) {
    float z = d * INV_T;
    float align   = logsig_neg(-z);
    float uniform = rowsum[n] * (1.0f / (float)M_);
    out[n]          = align + NEG_W * uniform;
    out[N_ + n]     = align;
    out[2 * N_ + n] = uniform;
  }
}

extern "C" void kernel_launch(void* const* d_in, const int* in_sizes, int n_in,
                              void* d_out, int out_size, void* d_ws,
                              size_t ws_size, hipStream_t stream) {
  const float* ref = (const float*)d_in[0];
  const float* pos = (const float*)d_in[1];
  const float* neg = (const float*)d_in[2];
  float* out = (float*)d_out;

  float* rowsum = (float*)d_ws;                                  // 32 KB
  unsigned short* abf = (unsigned short*)((char*)d_ws + 32768);  // 8 MB
  unsigned short* bbf = abf + (size_t)N_ * D_;                   // 8 MB

  (void)hipFuncSetAttribute((const void*)nce_gemm,
                            hipFuncAttributeMaxDynamicSharedMemorySize,
                            131072);

  hipMemsetAsync(rowsum, 0, N_ * sizeof(float), stream);
  cvt_pack<<<4096, 256, 0, stream>>>(ref, neg, abf, bbf);
  nce_gemm<<<1024, 512, 131072, stream>>>(abf, bbf, rowsum);
  nce_combine<<<N_ / 4, 256, 0, stream>>>(ref, pos, rowsum, out);
}

// Round 7
// 115.432 us; speedup vs baseline: 1.5274x; 1.0223x over previous
//
#include <hip/hip_runtime.h>

// NCE loss: out0 = align + w*uniform, out1 = align, out2 = uniform
// align[n]   = logsig(ref[n]·pos[n]/T)
// uniform[n] = mean_m logsig(-ref[n]·neg[m]/T)
// N=M=8192, D=512, T=0.5, w=1.0
//
// nce_gemm: 256x256 tile, BK=64, 8 waves (2x4), 16x16x32 MFMA, 8-phase
// schedule with counted vmcnt. Round 7: de-pinned — no lgkmcnt(0), no
// sched_barrier(0); raw s_barrier fused with vmcnt in one asm so the
// compiler software-pipelines ds_reads into the MFMA clusters with its
// own counted lgkmcnt (m97 mechanism; m141 showed pinning costs ~40%).

typedef __attribute__((ext_vector_type(8))) short short8;
typedef __attribute__((ext_vector_type(8))) unsigned short ushort8;
typedef __attribute__((ext_vector_type(4))) float f32x4;

constexpr int N_ = 8192;
constexpr int M_ = 8192;
constexpr int D_ = 512;
constexpr float INV_T = 2.0f;
constexpr float NEG_W = 1.0f;
constexpr float LOG2E = 1.4426950408889634f;
constexpr float LN2   = 0.6931471805599453f;

__device__ __forceinline__ unsigned short f2bf(float f) {
  unsigned int u = __builtin_bit_cast(unsigned int, f);
  u += 0x7FFFu + ((u >> 16) & 1u);  // RNE
  return (unsigned short)(u >> 16);
}

__device__ __forceinline__ float logsig_neg(float s) {
  // log sigmoid(-s) = min(-s,0) - log1p(exp(-|s|))
  float t = __builtin_fabsf(s);
  float e = __builtin_amdgcn_exp2f(-t * LOG2E);
  float l = __builtin_amdgcn_logf(1.0f + e) * LN2;
  return fminf(-s, 0.0f) - l;
}

// fp32 -> bf16 with intra-row 16B-chunk XOR involution pre-applied
// (chunk c stored at c ^ (row&7) within each 128B K-segment) so linear
// global_load_lds staging yields the swizzled LDS layout (rule #21).
__global__ __launch_bounds__(256) void cvt_pack(
    const float* __restrict__ refp, const float* __restrict__ negp,
    unsigned short* __restrict__ abf, unsigned short* __restrict__ bbf) {
  const int b = blockIdx.x;
  const float* src = (b < 2048) ? refp : negp;
  unsigned short* dst = (b < 2048) ? abf : bbf;
  const int i = (b & 2047) * 256 + threadIdx.x;  // 16B-chunk index
  const f32x4* s = reinterpret_cast<const f32x4*>(src) + (size_t)i * 2;
  f32x4 v0 = s[0], v1 = s[1];
  ushort8 o;
#pragma unroll
  for (int j = 0; j < 4; ++j) {
    o[j]     = f2bf(v0[j]);
    o[4 + j] = f2bf(v1[j]);
  }
  const unsigned int row = (unsigned int)i >> 6;
  const unsigned int seg = ((unsigned int)i >> 3) & 7;
  const unsigned int c   = (unsigned int)i & 7;
  const size_t byte =
      (size_t)row * 1024 + seg * 128 + (size_t)((c ^ (row & 7u)) << 4);
  *reinterpret_cast<ushort8*>(reinterpret_cast<char*>(dst) + byte) = o;
}

__global__ __launch_bounds__(512, 2) void nce_gemm(
    const unsigned short* __restrict__ A,  // ref bf16, pre-swizzled rows
    const unsigned short* __restrict__ B,  // neg bf16, pre-swizzled rows
    float* __restrict__ rowsum) {          // (N,) fp32, pre-zeroed
  extern __shared__ char lds[];
  char* As = lds;           // 2 bufs x 256 rows x 128 B
  char* Bs = lds + 65536;   // 2 bufs x 256 rows x 128 B

  const int tid  = threadIdx.x;
  const int lane = tid & 63;
  const int wid  = tid >> 6;   // 0..7
  const int wr   = wid >> 2;   // 0..1 (A half: 128 rows)
  const int wc   = wid & 3;    // 0..3 (B quarter: 64 cols)

  // XCD band swizzle: 1024 blocks, 8 XCDs, 4 row-bands/XCD, col-major in band
  const int bid  = blockIdx.x;
  const int x    = bid & 7;
  const int t    = bid >> 3;  // 0..127
  const int brow = (x * 4 + (t & 3)) * 256;
  const int bcol = (t >> 2) * 256;

  // staging lane address (global stored layout == desired LDS layout)
  const size_t laneoff = (size_t)(lane >> 3) * 1024 + (size_t)(lane & 7) * 16;
  const char* gA = reinterpret_cast<const char*>(A) + (size_t)brow * 1024 + laneoff;
  const char* gB = reinterpret_cast<const char*>(B) + (size_t)bcol * 1024 + laneoff;

  // fragment-read constants (proven conflict-free 16-lane pattern)
  const int r  = lane & 15;
  const int g4 = lane >> 4;
  const int c0 = ((g4 ^ (r & 7)) << 4);
  const int c1 = (((4 + g4) ^ (r & 7)) << 4);

  f32x4 acc[8][4] = {};
  short8 aLo[4][2], aHi[4][2], bv0[2][2], bv1[2][2];

  // ---- stage one half-tile (16 KiB), 2 glds per thread ----
  // A-sh h: rows [64h,64h+64) U [128+64h,192+64h)  (mp=h read rows)
#define STAGE_A(g, h)                                                         \
  {                                                                           \
    _Pragma("unroll") for (int j = 0; j < 2; ++j) {                           \
      const int u  = wid * 2 + j;                                             \
      const int rb = (u >> 3) * 128 + (u & 7) * 8 + (h) * 64;                 \
      __builtin_amdgcn_global_load_lds(                                       \
          (const __attribute__((address_space(1))) unsigned int*)(            \
              gA + (size_t)rb * 1024 + (size_t)((g) & 7) * 128),              \
          (__attribute__((address_space(3))) unsigned int*)(                  \
              As + ((g) & 1) * 32768 + rb * 128),                             \
          16, 0, 0);                                                          \
    }                                                                         \
  }
  // B-sh h: rows == [32h, 32h+32) mod 64  (nh=h read rows)
#define STAGE_B(g, h)                                                         \
  {                                                                           \
    _Pragma("unroll") for (int j = 0; j < 2; ++j) {                           \
      const int u  = wid * 2 + j;                                             \
      const int rb = (u >> 2) * 64 + (u & 3) * 8 + (h) * 32;                  \
      __builtin_amdgcn_global_load_lds(                                       \
          (const __attribute__((address_space(1))) unsigned int*)(            \
              gB + (size_t)rb * 1024 + (size_t)((g) & 7) * 128),              \
          (__attribute__((address_space(3))) unsigned int*)(                  \
              Bs + ((g) & 1) * 32768 + rb * 128),                             \
          16, 0, 0);                                                          \
    }                                                                         \
  }

#define READ_A(buf, mp, DST)                                                  \
  {                                                                           \
    _Pragma("unroll") for (int mf = 0; mf < 4; ++mf) {                        \
      const int ro = (wr * 128 + (mp)*64 + mf * 16 + r) * 128;                \
      DST[mf][0] =                                                            \
          *reinterpret_cast<const short8*>(As + (buf)*32768 + ro + c0);       \
      DST[mf][1] =                                                            \
          *reinterpret_cast<const short8*>(As + (buf)*32768 + ro + c1);       \
    }                                                                         \
  }
#define READ_B(buf, nh, DST)                                                  \
  {                                                                           \
    _Pragma("unroll") for (int nf = 0; nf < 2; ++nf) {                        \
      const int ro = (wc * 64 + (nh)*32 + nf * 16 + r) * 128;                 \
      DST[nf][0] =                                                            \
          *reinterpret_cast<const short8*>(Bs + (buf)*32768 + ro + c0);       \
      DST[nf][1] =                                                            \
          *reinterpret_cast<const short8*>(Bs + (buf)*32768 + ro + c1);       \
    }                                                                         \
  }

  // barriers: raw s_barrier fused with counted vmcnt; "memory" fences C++
  // LDS reads across the staging guarantee, but NO lgkmcnt(0) and NO
  // sched_barrier -> compiler interleaves ds_reads with MFMAs (counted lgkm)
#define WAITBAR()                                                             \
  asm volatile("s_waitcnt vmcnt(4)\n\ts_barrier" ::: "memory")
#define NOWAITBAR() asm volatile("s_barrier" ::: "memory")
#define ENDBAR()    asm volatile("s_barrier" ::: "memory")

#define CLUSTER(mp, nh, AV, BV)                                               \
  {                                                                           \
    __builtin_amdgcn_s_setprio(1);                                            \
    _Pragma("unroll") for (int k = 0; k < 2; ++k)                             \
    _Pragma("unroll") for (int mf = 0; mf < 4; ++mf)                          \
    _Pragma("unroll") for (int nf = 0; nf < 2; ++nf)                          \
      acc[(mp)*4 + mf][(nh)*2 + nf] = __builtin_amdgcn_mfma_f32_16x16x32_bf16(\
          AV[mf][k], BV[nf][k], acc[(mp)*4 + mf][(nh)*2 + nf], 0, 0, 0);      \
    __builtin_amdgcn_s_setprio(0);                                            \
  }

  // ---- prologue: tile 0 into buf0 (8 loads) ----
  STAGE_A(0, 0);
  STAGE_B(0, 0);
  STAGE_A(0, 1);
  STAGE_B(0, 1);
  WAITBAR();  // A-sh0,B-sh0 landed; sh1 covered by ph1/ph2 waits

  // ---- main loop: 4 iters x {tile e in buf0, tile e+1 in buf1} ----
  // vmcnt ledger identical to round 6 (each half-tile guaranteed one
  // phase before its first ds_read; dummy tail stages keep it uniform).
#pragma unroll
  for (int it = 0; it < 4; ++it) {
    const int e = 2 * it;
    // ph1: (m0,n0) of tile e
    READ_A(0, 0, aLo);
    READ_B(0, 0, bv0);
    STAGE_A(e + 1, 0);
    WAITBAR();          // retires A-sh1(buf0) -> read ph2
    CLUSTER(0, 0, aLo, bv0);
    ENDBAR();
    // ph2: (m1,n0)
    READ_A(0, 1, aHi);
    STAGE_B(e + 1, 0);
    WAITBAR();          // retires B-sh1(buf0) -> read ph3
    CLUSTER(1, 0, aHi, bv0);
    ENDBAR();
    // ph3: (m0,n1)
    READ_B(0, 1, bv1);
    STAGE_A(e + 1, 1);
    NOWAITBAR();
    CLUSTER(0, 1, aLo, bv1);
    ENDBAR();
    // ph4: (m1,n1)
    STAGE_B(e + 1, 1);
    WAITBAR();          // retires A-sh0,B-sh0(buf1) -> read ph5
    CLUSTER(1, 1, aHi, bv1);
    ENDBAR();
    // ph5: (m0,n0) of tile e+1
    READ_A(1, 0, aLo);
    READ_B(1, 0, bv0);
    STAGE_A(e + 2, 0);
    WAITBAR();          // retires A-sh1(buf1) -> read ph6
    CLUSTER(0, 0, aLo, bv0);
    ENDBAR();
    // ph6: (m1,n0)
    READ_A(1, 1, aHi);
    STAGE_B(e + 2, 0);
    WAITBAR();          // retires B-sh1(buf1) -> read ph7
    CLUSTER(1, 0, aHi, bv0);
    ENDBAR();
    // ph7: (m0,n1)
    READ_B(1, 1, bv1);
    STAGE_A(e + 2, 1);
    NOWAITBAR();
    CLUSTER(0, 1, aLo, bv1);
    ENDBAR();
    // ph8: (m1,n1)
    STAGE_B(e + 2, 1);
    WAITBAR();          // retires A-sh0,B-sh0(buf0 next) -> read next ph1
    CLUSTER(1, 1, aHi, bv1);
    ENDBAR();
  }
  asm volatile("s_waitcnt vmcnt(0)" ::: "memory");  // retire tail stages
#undef STAGE_A
#undef STAGE_B
#undef READ_A
#undef READ_B
#undef CLUSTER

  // ---- epilogue: uni = logsig(-s*INV_T); reduce this wave's 64 cols ----
  float part[32];
#pragma unroll
  for (int am = 0; am < 8; ++am)
#pragma unroll
    for (int rr = 0; rr < 4; ++rr) {
      float ssum = 0.0f;
#pragma unroll
      for (int an = 0; an < 4; ++an) {
        float s = acc[am][an][rr] * INV_T;
        ssum += logsig_neg(s);
      }
      part[am * 4 + rr] = ssum;
    }
#pragma unroll
  for (int i = 0; i < 32; ++i) {
    float v = part[i];
    v += __shfl_xor(v, 1);
    v += __shfl_xor(v, 2);
    v += __shfl_xor(v, 4);
    v += __shfl_xor(v, 8);
    part[i] = v;
  }
  if ((lane & 15) == 0) {
    const int gq = lane >> 4;  // row quad within fragment
#pragma unroll
    for (int am = 0; am < 8; ++am)
#pragma unroll
      for (int rr = 0; rr < 4; ++rr)
        atomicAdd(&rowsum[brow + wr * 128 + am * 16 + gq * 4 + rr],
                  part[am * 4 + rr]);
  }
}

__global__ __launch_bounds__(256) void nce_combine(
    const float* __restrict__ ref, const float* __restrict__ pos,
    const float* __restrict__ rowsum, float* __restrict__ out) {
  const int wid  = threadIdx.x >> 6;
  const int lane = threadIdx.x & 63;
  const int n    = blockIdx.x * 4 + wid;

  const f32x4* pr =
      reinterpret_cast<const f32x4*>(ref + (size_t)n * D_ + lane * 8);
  const f32x4* pp =
      reinterpret_cast<const f32x4*>(pos + (size_t)n * D_ + lane * 8);
  f32x4 a0 = pr[0], a1 = pr[1], b0 = pp[0], b1 = pp[1];
  float d = 0.0f;
#pragma unroll
  for (int i = 0; i < 4; ++i) d = __builtin_fmaf(a0[i], b0[i], d);
#pragma unroll
  for (int i = 0; i < 4; ++i) d = __builtin_fmaf(a1[i], b1[i], d);
#pragma unroll
  for (int s = 1; s < 64; s <<= 1) d += __shfl_xor(d, s);

  if (lane == 0) {
    float z = d * INV_T;
    float align   = logsig_neg(-z);
    float uniform = rowsum[n] * (1.0f / (float)M_);
    out[n]          = align + NEG_W * uniform;
    out[N_ + n]     = align;
    out[2 * N_ + n] = uniform;
  }
}

extern "C" void kernel_launch(void* const* d_in, const int* in_sizes, int n_in,
                              void* d_out, int out_size, void* d_ws,
                              size_t ws_size, hipStream_t stream) {
  const float* ref = (const float*)d_in[0];
  const float* pos = (const float*)d_in[1];
  const float* neg = (const float*)d_in[2];
  float* out = (float*)d_out;

  float* rowsum = (float*)d_ws;                                  // 32 KB
  unsigned short* abf = (unsigned short*)((char*)d_ws + 32768);  // 8 MB
  unsigned short* bbf = abf + (size_t)N_ * D_;                   // 8 MB

  (void)hipFuncSetAttribute((const void*)nce_gemm,
                            hipFuncAttributeMaxDynamicSharedMemorySize,
                            131072);

  hipMemsetAsync(rowsum, 0, N_ * sizeof(float), stream);
  cvt_pack<<<4096, 256, 0, stream>>>(ref, neg, abf, bbf);
  nce_gemm<<<1024, 512, 131072, stream>>>(abf, bbf, rowsum);
  nce_combine<<<N_ / 4, 256, 0, stream>>>(ref, pos, rowsum, out);
}

// Round 8
// 107.634 us; speedup vs baseline: 1.6380x; 1.0724x over previous
//
#include <hip/hip_runtime.h>

// NCE loss: out0 = align + w*uniform, out1 = align, out2 = uniform
// align[n]   = logsig(ref[n]·pos[n]/T)
// uniform[n] = mean_m logsig(-ref[n]·neg[m]/T)
// N=M=8192, D=512, T=0.5, w=1.0
//
// nce_gemm: 256x256 tile, BK=64, 8 waves (2x4), 16x16x32 MFMA, 8-phase
// counted-vmcnt schedule. Round 8: SINGLE barrier per phase (ENDBAR
// removed) so a wave issues phase p+1's ds_reads while phase p's MFMAs
// execute — LDS servicing overlaps MFMA + barrier skew instead of
// serializing (round-7 lockstep measured ~1970 cy/phase vs ~620 MFMA).

typedef __attribute__((ext_vector_type(8))) short short8;
typedef __attribute__((ext_vector_type(8))) unsigned short ushort8;
typedef __attribute__((ext_vector_type(4))) float f32x4;

constexpr int N_ = 8192;
constexpr int M_ = 8192;
constexpr int D_ = 512;
constexpr float INV_T = 2.0f;
constexpr float NEG_W = 1.0f;
constexpr float LOG2E = 1.4426950408889634f;
constexpr float LN2   = 0.6931471805599453f;

__device__ __forceinline__ unsigned short f2bf(float f) {
  unsigned int u = __builtin_bit_cast(unsigned int, f);
  u += 0x7FFFu + ((u >> 16) & 1u);  // RNE
  return (unsigned short)(u >> 16);
}

__device__ __forceinline__ float logsig_neg(float s) {
  // log sigmoid(-s) = min(-s,0) - log1p(exp(-|s|))
  float t = __builtin_fabsf(s);
  float e = __builtin_amdgcn_exp2f(-t * LOG2E);
  float l = __builtin_amdgcn_logf(1.0f + e) * LN2;
  return fminf(-s, 0.0f) - l;
}

// fp32 -> bf16 with intra-row 16B-chunk XOR involution pre-applied
// (chunk c stored at c ^ (row&7) within each 128B K-segment) so linear
// global_load_lds staging yields the swizzled LDS layout (rule #21).
__global__ __launch_bounds__(256) void cvt_pack(
    const float* __restrict__ refp, const float* __restrict__ negp,
    unsigned short* __restrict__ abf, unsigned short* __restrict__ bbf) {
  const int b = blockIdx.x;
  const float* src = (b < 2048) ? refp : negp;
  unsigned short* dst = (b < 2048) ? abf : bbf;
  const int i = (b & 2047) * 256 + threadIdx.x;  // 16B-chunk index
  const f32x4* s = reinterpret_cast<const f32x4*>(src) + (size_t)i * 2;
  f32x4 v0 = s[0], v1 = s[1];
  ushort8 o;
#pragma unroll
  for (int j = 0; j < 4; ++j) {
    o[j]     = f2bf(v0[j]);
    o[4 + j] = f2bf(v1[j]);
  }
  const unsigned int row = (unsigned int)i >> 6;
  const unsigned int seg = ((unsigned int)i >> 3) & 7;
  const unsigned int c   = (unsigned int)i & 7;
  const size_t byte =
      (size_t)row * 1024 + seg * 128 + (size_t)((c ^ (row & 7u)) << 4);
  *reinterpret_cast<ushort8*>(reinterpret_cast<char*>(dst) + byte) = o;
}

__global__ __launch_bounds__(512, 2) void nce_gemm(
    const unsigned short* __restrict__ A,  // ref bf16, pre-swizzled rows
    const unsigned short* __restrict__ B,  // neg bf16, pre-swizzled rows
    float* __restrict__ rowsum) {          // (N,) fp32, pre-zeroed
  extern __shared__ char lds[];
  char* As = lds;           // 2 bufs x 256 rows x 128 B
  char* Bs = lds + 65536;   // 2 bufs x 256 rows x 128 B

  const int tid  = threadIdx.x;
  const int lane = tid & 63;
  const int wid  = tid >> 6;   // 0..7
  const int wr   = wid >> 2;   // 0..1 (A half: 128 rows)
  const int wc   = wid & 3;    // 0..3 (B quarter: 64 cols)

  // XCD band swizzle: 1024 blocks, 8 XCDs, 4 row-bands/XCD, col-major in band
  const int bid  = blockIdx.x;
  const int x    = bid & 7;
  const int t    = bid >> 3;  // 0..127
  const int brow = (x * 4 + (t & 3)) * 256;
  const int bcol = (t >> 2) * 256;

  // staging lane address (global stored layout == desired LDS layout)
  const size_t laneoff = (size_t)(lane >> 3) * 1024 + (size_t)(lane & 7) * 16;
  const char* gA = reinterpret_cast<const char*>(A) + (size_t)brow * 1024 + laneoff;
  const char* gB = reinterpret_cast<const char*>(B) + (size_t)bcol * 1024 + laneoff;

  // fragment-read constants (proven conflict-free 16-lane pattern)
  const int r  = lane & 15;
  const int g4 = lane >> 4;
  const int c0 = ((g4 ^ (r & 7)) << 4);
  const int c1 = (((4 + g4) ^ (r & 7)) << 4);

  f32x4 acc[8][4] = {};
  short8 aLo[4][2], aHi[4][2], bv0[2][2], bv1[2][2];

  // ---- stage one half-tile (16 KiB), 2 glds per thread ----
  // A-sh h: rows [64h,64h+64) U [128+64h,192+64h)  (mp=h read rows)
#define STAGE_A(g, h)                                                         \
  {                                                                           \
    _Pragma("unroll") for (int j = 0; j < 2; ++j) {                           \
      const int u  = wid * 2 + j;                                             \
      const int rb = (u >> 3) * 128 + (u & 7) * 8 + (h) * 64;                 \
      __builtin_amdgcn_global_load_lds(                                       \
          (const __attribute__((address_space(1))) unsigned int*)(            \
              gA + (size_t)rb * 1024 + (size_t)((g) & 7) * 128),              \
          (__attribute__((address_space(3))) unsigned int*)(                  \
              As + ((g) & 1) * 32768 + rb * 128),                             \
          16, 0, 0);                                                          \
    }                                                                         \
  }
  // B-sh h: rows == [32h, 32h+32) mod 64  (nh=h read rows)
#define STAGE_B(g, h)                                                         \
  {                                                                           \
    _Pragma("unroll") for (int j = 0; j < 2; ++j) {                           \
      const int u  = wid * 2 + j;                                             \
      const int rb = (u >> 2) * 64 + (u & 3) * 8 + (h) * 32;                  \
      __builtin_amdgcn_global_load_lds(                                       \
          (const __attribute__((address_space(1))) unsigned int*)(            \
              gB + (size_t)rb * 1024 + (size_t)((g) & 7) * 128),              \
          (__attribute__((address_space(3))) unsigned int*)(                  \
              Bs + ((g) & 1) * 32768 + rb * 128),                             \
          16, 0, 0);                                                          \
    }                                                                         \
  }

#define READ_A(buf, mp, DST)                                                  \
  {                                                                           \
    _Pragma("unroll") for (int mf = 0; mf < 4; ++mf) {                        \
      const int ro = (wr * 128 + (mp)*64 + mf * 16 + r) * 128;                \
      DST[mf][0] =                                                            \
          *reinterpret_cast<const short8*>(As + (buf)*32768 + ro + c0);       \
      DST[mf][1] =                                                            \
          *reinterpret_cast<const short8*>(As + (buf)*32768 + ro + c1);       \
    }                                                                         \
  }
#define READ_B(buf, nh, DST)                                                  \
  {                                                                           \
    _Pragma("unroll") for (int nf = 0; nf < 2; ++nf) {                        \
      const int ro = (wc * 64 + (nh)*32 + nf * 16 + r) * 128;                 \
      DST[nf][0] =                                                            \
          *reinterpret_cast<const short8*>(Bs + (buf)*32768 + ro + c0);       \
      DST[nf][1] =                                                            \
          *reinterpret_cast<const short8*>(Bs + (buf)*32768 + ro + c1);       \
    }                                                                         \
  }

  // single barrier per phase: vmcnt (counted, never 0 in-loop) fused with
  // s_barrier. No second barrier after MFMA -> next phase's ds_reads issue
  // while this phase's MFMAs execute.
#define WAITBAR()                                                             \
  asm volatile("s_waitcnt vmcnt(4)\n\ts_barrier" ::: "memory")
#define NOWAITBAR() asm volatile("s_barrier" ::: "memory")

#define CLUSTER(mp, nh, AV, BV)                                               \
  {                                                                           \
    __builtin_amdgcn_s_setprio(1);                                            \
    _Pragma("unroll") for (int k = 0; k < 2; ++k)                             \
    _Pragma("unroll") for (int mf = 0; mf < 4; ++mf)                          \
    _Pragma("unroll") for (int nf = 0; nf < 2; ++nf)                          \
      acc[(mp)*4 + mf][(nh)*2 + nf] = __builtin_amdgcn_mfma_f32_16x16x32_bf16(\
          AV[mf][k], BV[nf][k], acc[(mp)*4 + mf][(nh)*2 + nf], 0, 0, 0);      \
    __builtin_amdgcn_s_setprio(0);                                            \
  }

  // ---- prologue: tile 0 into buf0 (8 loads) ----
  STAGE_A(0, 0);
  STAGE_B(0, 0);
  STAGE_A(0, 1);
  STAGE_B(0, 1);
  WAITBAR();  // retires A0h0,B0h0 -> ph1 reads safe

  // ---- main loop: 4 iters x {tile e in buf0, tile e+1 in buf1} ----
  // vmcnt ledger (verified): each half-tile retires exactly one barrier
  // before its first ds_read; steady-state 4-6 glds in flight.
#pragma unroll
  for (int it = 0; it < 4; ++it) {
    const int e = 2 * it;
    // ph1: (m0,n0) of tile e
    READ_A(0, 0, aLo);
    READ_B(0, 0, bv0);
    STAGE_A(e + 1, 0);
    WAITBAR();          // retires A-sh1(buf0) -> read ph2
    CLUSTER(0, 0, aLo, bv0);
    // ph2: (m1,n0)
    READ_A(0, 1, aHi);
    STAGE_B(e + 1, 0);
    WAITBAR();          // retires B-sh1(buf0) -> read ph3
    CLUSTER(1, 0, aHi, bv0);
    // ph3: (m0,n1)
    READ_B(0, 1, bv1);
    STAGE_A(e + 1, 1);
    NOWAITBAR();
    CLUSTER(0, 1, aLo, bv1);
    // ph4: (m1,n1)
    STAGE_B(e + 1, 1);
    WAITBAR();          // retires A-sh0,B-sh0(buf1) -> read ph5
    CLUSTER(1, 1, aHi, bv1);
    // ph5: (m0,n0) of tile e+1
    READ_A(1, 0, aLo);
    READ_B(1, 0, bv0);
    STAGE_A(e + 2, 0);
    WAITBAR();          // retires A-sh1(buf1) -> read ph6
    CLUSTER(0, 0, aLo, bv0);
    // ph6: (m1,n0)
    READ_A(1, 1, aHi);
    STAGE_B(e + 2, 0);
    WAITBAR();          // retires B-sh1(buf1) -> read ph7
    CLUSTER(1, 0, aHi, bv0);
    // ph7: (m0,n1)
    READ_B(1, 1, bv1);
    STAGE_A(e + 2, 1);
    NOWAITBAR();
    CLUSTER(0, 1, aLo, bv1);
    // ph8: (m1,n1)
    STAGE_B(e + 2, 1);
    WAITBAR();          // retires A-sh0,B-sh0(buf0 next) -> read next ph1
    CLUSTER(1, 1, aHi, bv1);
  }
  asm volatile("s_waitcnt vmcnt(0)" ::: "memory");  // retire tail stages
#undef STAGE_A
#undef STAGE_B
#undef READ_A
#undef READ_B
#undef CLUSTER

  // ---- epilogue: uni = logsig(-s*INV_T); reduce this wave's 64 cols ----
  float part[32];
#pragma unroll
  for (int am = 0; am < 8; ++am)
#pragma unroll
    for (int rr = 0; rr < 4; ++rr) {
      float ssum = 0.0f;
#pragma unroll
      for (int an = 0; an < 4; ++an) {
        float s = acc[am][an][rr] * INV_T;
        ssum += logsig_neg(s);
      }
      part[am * 4 + rr] = ssum;
    }
#pragma unroll
  for (int i = 0; i < 32; ++i) {
    float v = part[i];
    v += __shfl_xor(v, 1);
    v += __shfl_xor(v, 2);
    v += __shfl_xor(v, 4);
    v += __shfl_xor(v, 8);
    part[i] = v;
  }
  if ((lane & 15) == 0) {
    const int gq = lane >> 4;  // row quad within fragment
#pragma unroll
    for (int am = 0; am < 8; ++am)
#pragma unroll
      for (int rr = 0; rr < 4; ++rr)
        atomicAdd(&rowsum[brow + wr * 128 + am * 16 + gq * 4 + rr],
                  part[am * 4 + rr]);
  }
}

__global__ __launch_bounds__(256) void nce_combine(
    const float* __restrict__ ref, const float* __restrict__ pos,
    const float* __restrict__ rowsum, float* __restrict__ out) {
  const int wid  = threadIdx.x >> 6;
  const int lane = threadIdx.x & 63;
  const int n    = blockIdx.x * 4 + wid;

  const f32x4* pr =
      reinterpret_cast<const f32x4*>(ref + (size_t)n * D_ + lane * 8);
  const f32x4* pp =
      reinterpret_cast<const f32x4*>(pos + (size_t)n * D_ + lane * 8);
  f32x4 a0 = pr[0], a1 = pr[1], b0 = pp[0], b1 = pp[1];
  float d = 0.0f;
#pragma unroll
  for (int i = 0; i < 4; ++i) d = __builtin_fmaf(a0[i], b0[i], d);
#pragma unroll
  for (int i = 0; i < 4; ++i) d = __builtin_fmaf(a1[i], b1[i], d);
#pragma unroll
  for (int s = 1; s < 64; s <<= 1) d += __shfl_xor(d, s);

  if (lane == 0) {
    float z = d * INV_T;
    float align   = logsig_neg(-z);
    float uniform = rowsum[n] * (1.0f / (float)M_);
    out[n]          = align + NEG_W * uniform;
    out[N_ + n]     = align;
    out[2 * N_ + n] = uniform;
  }
}

extern "C" void kernel_launch(void* const* d_in, const int* in_sizes, int n_in,
                              void* d_out, int out_size, void* d_ws,
                              size_t ws_size, hipStream_t stream) {
  const float* ref = (const float*)d_in[0];
  const float* pos = (const float*)d_in[1];
  const float* neg = (const float*)d_in[2];
  float* out = (float*)d_out;

  float* rowsum = (float*)d_ws;                                  // 32 KB
  unsigned short* abf = (unsigned short*)((char*)d_ws + 32768);  // 8 MB
  unsigned short* bbf = abf + (size_t)N_ * D_;                   // 8 MB

  (void)hipFuncSetAttribute((const void*)nce_gemm,
                            hipFuncAttributeMaxDynamicSharedMemorySize,
                            131072);

  hipMemsetAsync(rowsum, 0, N_ * sizeof(float), stream);
  cvt_pack<<<4096, 256, 0, stream>>>(ref, neg, abf, bbf);
  nce_gemm<<<1024, 512, 131072, stream>>>(abf, bbf, rowsum);
  nce_combine<<<N_ / 4, 256, 0, stream>>>(ref, pos, rowsum, out);
}